// Round 1
// baseline (69.559 us; speedup 1.0000x reference)
//
#include <hip/hip_runtime.h>

// Spherical-harmonic (l=0..3) Zernike monomials + per-degree 4-unit dense,
// fused into one write-BW-bound elementwise kernel.
//
// Output layout: [B, N, 16, 4] f32, m-rows:
//   m=0    : C0*(W0[0,u] + n2*W0[1,u]) + b0[u]
//   m=1..3 : Y1[m] * (W1[0,u] + n2*W1[1,u]),  Y1 = C1*{py,pz,px}
//   m=4..8 : Y2[m] * W2[0,u]
//   m=9..15: Y3[m] * W3[0,u]
// One thread per (point, m): writes one float4 -> fully coalesced 1KB/wave stores.

#define C0f   0.28209479177387814f
#define C1f   0.4886025119029199f
#define C2XYf 1.0925484305920792f
#define C20f  0.31539156525252005f
#define C22f  0.5462742152960396f
#define C33f  0.5900435899266435f
#define C32f  2.890611442640554f
#define C31f  0.4570457994644658f
#define C30f  0.3731763325901154f
#define C3P2f 1.445305721320277f

__global__ __launch_bounds__(256) void zernike_dense_kernel(
    const float* __restrict__ x,
    const float* __restrict__ W0, const float* __restrict__ b0,
    const float* __restrict__ W1, const float* __restrict__ W2,
    const float* __restrict__ W3,
    float4* __restrict__ out, int ntasks)
{
    // Wave-uniform weight prep (compiler emits scalar loads; hoisted out of loop).
    float w00[4], w01[4], bb[4], w10[4], w11[4], w2r[4], w3r[4];
#pragma unroll
    for (int u = 0; u < 4; ++u) {
        w00[u] = C0f * W0[u];      // C0 * W0[0,:]
        w01[u] = C0f * W0[4 + u];  // C0 * W0[1,:]
        bb[u]  = b0[u];
        w10[u] = W1[u];
        w11[u] = W1[4 + u];
        w2r[u] = W2[u];
        w3r[u] = W3[u];
    }

    const int stride = gridDim.x * blockDim.x;
    for (int i = blockIdx.x * blockDim.x + threadIdx.x; i < ntasks; i += stride) {
        const int p = i >> 4;     // point index
        const int m = i & 15;     // output row 0..15

        const float px = x[3 * p + 0];
        const float py = x[3 * p + 1];
        const float pz = x[3 * p + 2];

        const float x2 = px * px, y2 = py * py, z2 = pz * pz;
        const float n2 = x2 + y2 + z2;

        // All 15 nontrivial SH row scalars (cheap straight-line VALU).
        const float sv1  = C1f * py;
        const float sv2  = C1f * pz;
        const float sv3  = C1f * px;
        const float sv4  = C2XYf * px * py;
        const float sv5  = C2XYf * py * pz;
        const float sv6  = C20f * (2.0f * z2 - x2 - y2);
        const float sv7  = C2XYf * px * pz;
        const float sv8  = C22f * (x2 - y2);
        const float sv9  = C33f * py * (3.0f * x2 - y2);
        const float sv10 = C32f * px * py * pz;
        const float sv11 = C31f * py * (4.0f * z2 - x2 - y2);
        const float sv12 = C30f * pz * (2.0f * z2 - 3.0f * x2 - 3.0f * y2);
        const float sv13 = C31f * px * (4.0f * z2 - x2 - y2);
        const float sv14 = C3P2f * pz * (x2 - y2);
        const float sv15 = C33f * px * (x2 - 3.0f * y2);

        // Branchless binary select tree (v_cndmask chain, no divergence).
        const float s =
            m < 8 ? (m < 4 ? (m < 2 ? (m == 0 ? 1.0f : sv1)
                                    : (m == 2 ? sv2 : sv3))
                           : (m < 6 ? (m == 4 ? sv4 : sv5)
                                    : (m == 6 ? sv6 : sv7)))
                  : (m < 12 ? (m < 10 ? (m == 8 ? sv8 : sv9)
                                      : (m == 10 ? sv10 : sv11))
                            : (m < 14 ? (m == 12 ? sv12 : sv13)
                                      : (m == 14 ? sv14 : sv15)));

        const bool is0  = (m == 0);
        const bool le3  = (m < 4);
        const bool le8  = (m < 9);

        float4 r;
        float* rp = &r.x;
#pragma unroll
        for (int u = 0; u < 4; ++u) {
            const float wa = is0 ? w00[u] : (le3 ? w10[u] : (le8 ? w2r[u] : w3r[u]));
            const float wb = is0 ? w01[u] : (le3 ? w11[u] : 0.0f);
            const float ad = is0 ? bb[u] : 0.0f;
            const float t  = fmaf(n2, wb, wa);
            rp[u] = fmaf(s, t, ad);
        }
        out[i] = r;
    }
}

extern "C" void kernel_launch(void* const* d_in, const int* in_sizes, int n_in,
                              void* d_out, int out_size, void* d_ws, size_t ws_size,
                              hipStream_t stream) {
    const float* x  = (const float*)d_in[0];
    const float* W0 = (const float*)d_in[1];
    const float* b0 = (const float*)d_in[2];
    const float* W1 = (const float*)d_in[3];
    const float* W2 = (const float*)d_in[4];
    const float* W3 = (const float*)d_in[5];

    const int ntasks = out_size / 4;      // one float4 per (point, m)
    const int threads = 256;
    const int blocks  = 4096;             // grid-stride, ~16 iters/thread

    zernike_dense_kernel<<<blocks, threads, 0, stream>>>(
        x, W0, b0, W1, W2, W3, (float4*)d_out, ntasks);
}

// Round 2
// 48.709 us; speedup vs baseline: 1.4280x; 1.4280x over previous
//
#include <hip/hip_runtime.h>

// Zernike SH (l=0..3) + per-degree 4-unit dense, fused, write-BW-bound.
//
// Two-phase LDS design (removes the 16x redundant SH compute of R0):
//  Phase 1: thread = point. Compute n2 + 15 SH scalars once; pre-fold
//           row0 final values G0[4] and l=1 factor G1[4]; write a 24-f32
//           record per point to LDS (96 B, b128-aligned).
//  Phase 2: thread-task = one (point, m) float4 output.
//           s = rec[8+m] (s0=1), H = m<4 ? LDS float4 (G0|G1)
//                                       : (m<9 ? W2 : W3 in regs)
//           out = s * H  -> ~20 instr / 16 B task, 1 KB/wave coalesced stores.

#define C0f   0.28209479177387814f
#define C1f   0.4886025119029199f
#define C2XYf 1.0925484305920792f
#define C20f  0.31539156525252005f
#define C22f  0.5462742152960396f
#define C33f  0.5900435899266435f
#define C32f  2.890611442640554f
#define C31f  0.4570457994644658f
#define C30f  0.3731763325901154f
#define C3P2f 1.445305721320277f

#define PTS_PER_BLOCK 256
#define REC 24  // floats per point record: [0:4)=G0(final row0), [4:8)=G1, [8:24)=s0..s15

__global__ __launch_bounds__(256) void zernike_fused(
    const float* __restrict__ x,
    const float* __restrict__ W0, const float* __restrict__ b0,
    const float* __restrict__ W1, const float* __restrict__ W2,
    const float* __restrict__ W3,
    float4* __restrict__ out, int npoints)
{
    __shared__ float sm[PTS_PER_BLOCK * REC];

    const int tid   = threadIdx.x;
    const int pbase = blockIdx.x * PTS_PER_BLOCK;

    // Wave-uniform weight prep (scalar loads; hoisted).
    float a0[4], a1[4], g10[4], g11[4], w2r[4], w3r[4];
#pragma unroll
    for (int u = 0; u < 4; ++u) {
        a0[u]  = C0f * W0[u] + b0[u];   // row0 = a0 + n2*a1 (bias folded)
        a1[u]  = C0f * W0[4 + u];
        g10[u] = W1[u];                 // l=1 factor = g10 + n2*g11
        g11[u] = W1[4 + u];
        w2r[u] = W2[u];
        w3r[u] = W3[u];
    }

    // ---- Phase 1: one point per thread ----
    {
        const int p = pbase + tid;
        if (p < npoints) {
            const float px = x[3 * p + 0];
            const float py = x[3 * p + 1];
            const float pz = x[3 * p + 2];
            const float x2 = px * px, y2 = py * py, z2 = pz * pz;
            const float n2 = x2 + y2 + z2;

            float* rec = &sm[tid * REC];

            float4 G0, G1;
            G0.x = fmaf(n2, a1[0], a0[0]);  G0.y = fmaf(n2, a1[1], a0[1]);
            G0.z = fmaf(n2, a1[2], a0[2]);  G0.w = fmaf(n2, a1[3], a0[3]);
            G1.x = fmaf(n2, g11[0], g10[0]); G1.y = fmaf(n2, g11[1], g10[1]);
            G1.z = fmaf(n2, g11[2], g10[2]); G1.w = fmaf(n2, g11[3], g10[3]);
            *(float4*)(rec + 0) = G0;
            *(float4*)(rec + 4) = G1;

            rec[8]  = 1.0f;                                       // s0 (row0 uses G0 directly)
            rec[9]  = C1f * py;
            rec[10] = C1f * pz;
            rec[11] = C1f * px;
            rec[12] = C2XYf * px * py;
            rec[13] = C2XYf * py * pz;
            rec[14] = C20f * (2.0f * z2 - x2 - y2);
            rec[15] = C2XYf * px * pz;
            rec[16] = C22f * (x2 - y2);
            rec[17] = C33f * py * (3.0f * x2 - y2);
            rec[18] = C32f * px * py * pz;
            rec[19] = C31f * py * (4.0f * z2 - x2 - y2);
            rec[20] = C30f * pz * (2.0f * z2 - 3.0f * x2 - 3.0f * y2);
            rec[21] = C31f * px * (4.0f * z2 - x2 - y2);
            rec[22] = C3P2f * pz * (x2 - y2);
            rec[23] = C33f * px * (x2 - 3.0f * y2);
        }
    }
    __syncthreads();

    // ---- Phase 2: one (point, m) float4 per thread-task, 16 tasks/thread ----
    const int obase = blockIdx.x * (PTS_PER_BLOCK * 16);  // float4 units
#pragma unroll 4
    for (int k = 0; k < 16; ++k) {
        const int t  = k * 256 + tid;
        const int pl = t >> 4;       // local point 0..255
        const int m  = t & 15;       // output row

        const float* rec = &sm[pl * REC];
        const float  s   = rec[8 + m];
        // H from LDS for m<4 (G0 for m==0, else G1); else W2/W3 from regs.
        const float4 hl  = *(const float4*)(rec + (m == 0 ? 0 : 4));

        float4 r;
        float*       rp = &r.x;
        const float* hp = &hl.x;
#pragma unroll
        for (int u = 0; u < 4; ++u) {
            const float hreg = (m < 9) ? w2r[u] : w3r[u];
            const float h    = (m < 4) ? hp[u] : hreg;
            rp[u] = s * h;
        }
        out[obase + t] = r;
    }
}

extern "C" void kernel_launch(void* const* d_in, const int* in_sizes, int n_in,
                              void* d_out, int out_size, void* d_ws, size_t ws_size,
                              hipStream_t stream) {
    const float* x  = (const float*)d_in[0];
    const float* W0 = (const float*)d_in[1];
    const float* b0 = (const float*)d_in[2];
    const float* W1 = (const float*)d_in[3];
    const float* W2 = (const float*)d_in[4];
    const float* W3 = (const float*)d_in[5];

    const int npoints = in_sizes[0] / 3;                 // 1,048,576
    const int blocks  = (npoints + PTS_PER_BLOCK - 1) / PTS_PER_BLOCK;  // 4096

    zernike_fused<<<blocks, 256, 0, stream>>>(
        x, W0, b0, W1, W2, W3, (float4*)d_out, npoints);
}